// Round 21
// baseline (67.021 us; speedup 1.0000x reference)
//
#include <hip/hip_runtime.h>

// Problem constants (B,C,H,W,K) = (32,192,56,56,7)
#define BB 32
#define CC 192
#define HH 56
#define WW 56
#define KS 7
#define HW 3136        // 56*56
#define KK 49
#define CKK 9408       // C*K*K
#define NCELL (BB * CC * KK)   // 301056
#define NBC (BB * CC)          // 6144
#define MIDBLK 24              // mid blocks per sample
#define TABW 56                // u32 words per channel in tap table
#define XP 2048                // u32 words per channel in x16 (32 rowpairs x 64)

typedef _Float16 h2 __attribute__((ext_vector_type(2)));   // for fdot2 only

__device__ __forceinline__ unsigned int pack16(float a, float b) {
    return __builtin_bit_cast(unsigned int, __builtin_amdgcn_cvt_pkrtz(a, b));
}

// ---------------------------------------------------------------------------
// K1: WAVE-PER-CHANNEL pool + x16 emit + per-channel LN0 partial.
// Lane = column. Per 8-row group i: 8 coalesced dword loads; 4 coalesced u32
// x16 stores (rowpair pack, cw = lane+4); 8-lane shfl_xor group sum -> pool
// cell (i, lane/8) on lanes 0,8,..,48. Halo: 4 full-row stores + 224 edge
// words. One float2 LN0 partial per channel.
// ---------------------------------------------------------------------------
__global__ __launch_bounds__(256) void pool_kernel(const float* __restrict__ x,
                                                   float* __restrict__ p0,
                                                   float2* __restrict__ part0c,
                                                   unsigned int* __restrict__ x16) {
    int lane = threadIdx.x & 63;
    int bc   = blockIdx.x * 4 + (threadIdx.x >> 6);
    const float* src = x + (size_t)bc * HW;
    unsigned int* xp = x16 + (size_t)bc * XP;
    bool act = lane < WW;
    int cl   = act ? lane : WW - 1;

    float sv = 0.f, sq = 0.f;
#pragma unroll
    for (int i = 0; i < 7; ++i) {
        float v[8];
#pragma unroll
        for (int r = 0; r < 8; ++r)
            v[r] = src[(8 * i + r) * WW + cl];       // coalesced 224B/row

        // x16: natural rowpairs {8i+2p, 8i+2p+1} -> pr2 = 4i+p+2, cw = lane+4
#pragma unroll
        for (int p = 0; p < 4; ++p) {
            unsigned int w = pack16(v[2 * p], v[2 * p + 1]);
            if (act) xp[(4 * i + p + 2) * 64 + 4 + lane] = w;
        }

        // pool: 8-row column sum, then 8-lane group sum
        float cs = ((v[0] + v[1]) + (v[2] + v[3])) + ((v[4] + v[5]) + (v[6] + v[7]));
        cs += __shfl_xor(cs, 1, 64);
        cs += __shfl_xor(cs, 2, 64);
        cs += __shfl_xor(cs, 4, 64);
        if (act && (lane & 7) == 0) {
            float pv = cs * (1.f / 64.f);
            p0[(size_t)bc * KK + i * KS + (lane >> 3)] = pv;
            sv += pv; sq += pv * pv;
        }
    }

    // ---- halo zeros: full rowpairs 0,1,30,31 + edge words of pr2 2..29 ----
    xp[0 * 64 + lane]  = 0u;
    xp[1 * 64 + lane]  = 0u;
    xp[30 * 64 + lane] = 0u;
    xp[31 * 64 + lane] = 0u;
#pragma unroll
    for (int t = 0; t < 4; ++t) {
        int idx = t * 64 + lane;                     // 0..255, need < 224
        if (idx < 224) {
            int pr2 = 2 + (idx >> 3);
            int j = idx & 7;
            xp[pr2 * 64 + (j < 4 ? j : 56 + j)] = 0u;
        }
    }

    // ---- per-channel LN0 partial ----
#pragma unroll
    for (int o = 32; o > 0; o >>= 1) {
        sv += __shfl_down(sv, o, 64);
        sq += __shfl_down(sq, o, 64);
    }
    if (lane == 0) part0c[bc] = make_float2(sv, sq);
}

// ---------------------------------------------------------------------------
// K2: LN0-normalize + depthwise 7x7 conv on the 7x7 map, one WAVE per (b,c).
// Stats0 from 192 per-channel partials (3 per lane, exact).
// ---------------------------------------------------------------------------
__global__ __launch_bounds__(512) void mid_kernel(
    const float* __restrict__ p0,
    const float* __restrict__ ln0w, const float* __restrict__ ln0b,
    const float* __restrict__ w0,
    const float2* __restrict__ part0c,
    float* __restrict__ q1,
    float2* __restrict__ part1)
{
    __shared__ float red[16];
    int tid  = threadIdx.x;
    int lane = tid & 63;
    int bc   = blockIdx.x * 8 + (tid >> 6);
    int b = bc / CC;
    int c = bc - b * CC;

    float s0 = 0.f, ss0 = 0.f;
#pragma unroll
    for (int t = 0; t < 3; ++t) {
        float2 p = part0c[b * CC + lane + 64 * t];   // 192 = 3*64 exact
        s0 += p.x; ss0 += p.y;
    }
#pragma unroll
    for (int o = 32; o > 0; o >>= 1) {
        s0  += __shfl_down(s0, o, 64);
        ss0 += __shfl_down(ss0, o, 64);
    }
    s0  = __shfl(s0, 0, 64);
    ss0 = __shfl(ss0, 0, 64);
    float mean = s0 * (1.f / CKK);
    float rstd = rsqrtf(ss0 * (1.f / CKK) - mean * mean + 1e-5f);

    float val = 0.f;
    if (lane < KK)
        val = (p0[(size_t)bc * KK + lane] - mean) * rstd * ln0w[c * KK + lane]
              + ln0b[c * KK + lane];

    int i0 = lane / KS;
    int j0 = lane - i0 * KS;
    const float* wc = w0 + c * KK;

    float acc = 0.f;
#pragma unroll
    for (int u = 0; u < KS; ++u) {
        int ii = i0 + u - 3;
#pragma unroll
        for (int v = 0; v < KS; ++v) {
            int jj = j0 + v - 3;
            bool ok = (ii >= 0) && (ii < KS) && (jj >= 0) && (jj < KS);
            int sl = ok ? (ii * KS + jj) : 0;
            float sv = __shfl(val, sl, 64);
            acc += ok ? sv * wc[u * KS + v] : 0.f;
        }
    }
    if (lane >= KK) acc = 0.f;
    if (lane < KK) q1[(size_t)bc * KK + lane] = acc;

    float s2 = acc, ss2 = acc * acc;
#pragma unroll
    for (int o = 32; o > 0; o >>= 1) {
        s2  += __shfl_down(s2, o, 64);
        ss2 += __shfl_down(ss2, o, 64);
    }
    if (lane == 0) {
        red[(tid >> 6) * 2 + 0] = s2;
        red[(tid >> 6) * 2 + 1] = ss2;
    }
    __syncthreads();
    if (tid == 0) {
        float a = 0.f, q = 0.f;
#pragma unroll
        for (int w = 0; w < 8; ++w) { a += red[2 * w]; q += red[2 * w + 1]; }
        part1[blockIdx.x] = make_float2(a, q);
    }
}

// ---------------------------------------------------------------------------
// K3: tab_kernel — LN1+ReLU taps -> NATURAL-PAIRING tap tables (1 wave/bc).
//   ktab[bc][0..27]  dt[e*7+v] = h2{ e>0 ? kt[2e-1][v] : 0, kt[2e][v] }
//   ktab[bc][28..55] ct[e*7+v] = h2{ kt[2e][v], e<3 ? kt[2e+1][v] : 0 }
// ---------------------------------------------------------------------------
__global__ __launch_bounds__(256) void tab_kernel(
    const float* __restrict__ q1, const float2* __restrict__ part1,
    const float* __restrict__ ln1w, const float* __restrict__ ln1b,
    unsigned int* __restrict__ ktab)
{
    int lane = threadIdx.x & 63;
    int bc   = blockIdx.x * 4 + (threadIdx.x >> 6);
    int b = bc / CC;
    int c = bc - b * CC;

    float s1 = 0.f, ss1 = 0.f;
    if (lane < MIDBLK) {
        float2 p = part1[b * MIDBLK + lane];
        s1 = p.x; ss1 = p.y;
    }
#pragma unroll
    for (int o = 32; o > 0; o >>= 1) {
        s1  += __shfl_down(s1, o, 64);
        ss1 += __shfl_down(ss1, o, 64);
    }
    s1  = __shfl(s1, 0, 64);
    ss1 = __shfl(ss1, 0, 64);
    float m = s1 * (1.f / CKK);
    float r = rsqrtf(ss1 * (1.f / CKK) - m * m + 1e-5f);

    float kt = 0.f;
    if (lane < KK) {
        float v = (q1[(size_t)bc * KK + lane] - m) * r * ln1w[c * KK + lane]
                  + ln1b[c * KK + lane];
        kt = v > 0.f ? v : 0.f;
    }

    bool isDt = lane < 28;
    int idx = isDt ? lane : (lane < TABW ? lane - 28 : 0);
    int e = idx / KS, v = idx - KS * e;
    int iA, iB; bool mA, mB;
    if (isDt) { mA = (e > 0); iA = mA ? (2 * e - 1) * KS + v : 0;
                mB = true;    iB = 2 * e * KS + v; }
    else      { mA = true;    iA = 2 * e * KS + v;
                mB = (e < 3); iB = mB ? (2 * e + 1) * KS + v : 0; }
    float va = __shfl(kt, iA, 64);
    float vb = __shfl(kt, iB, 64);
    unsigned int w = pack16(mA ? va : 0.f, mB ? vb : 0.f);
    if (lane < TABW)
        ktab[(size_t)bc * TABW + lane] = w;
}

// ---------------------------------------------------------------------------
// K4: per-(b,c) depthwise 7x7 SAME conv — NO LDS, NO BARRIER (R20-verified).
// Reads pre-packed x16 directly; lane owns output col; 392 dot2/wave.
// ---------------------------------------------------------------------------
__global__ __launch_bounds__(256) void conv_kernel(
    const unsigned int* __restrict__ x16,
    const unsigned int* __restrict__ ktab,
    float* __restrict__ out)
{
    int bc   = blockIdx.x;
    int tid  = threadIdx.x;
    int lane = tid & 63;
    int wid  = tid >> 6;

    // ---- tap tables (block-uniform -> s_load / SGPRs) ----
    const uint4* tb = (const uint4*)(ktab + (size_t)bc * TABW);
    unsigned int dt[28], ct[28];
#pragma unroll
    for (int i = 0; i < 7; ++i) {
        uint4 t4 = tb[i];
        dt[4 * i + 0] = t4.x; dt[4 * i + 1] = t4.y;
        dt[4 * i + 2] = t4.z; dt[4 * i + 3] = t4.w;
    }
#pragma unroll
    for (int i = 0; i < 7; ++i) {
        uint4 t4 = tb[7 + i];
        ct[4 * i + 0] = t4.x; ct[4 * i + 1] = t4.y;
        ct[4 * i + 2] = t4.z; ct[4 * i + 3] = t4.w;
    }

    int ll = lane < 56 ? lane : 55;      // clamp: lanes 56-63 duplicate lane 55
    const unsigned int* base = x16 + (size_t)bc * XP + (wid * 7) * 64 + ll + 1;

    float accL[7], accH[7];
#pragma unroll
    for (int t = 0; t < 7; ++t) { accL[t] = 0.f; accH[t] = 0.f; }

    unsigned int wa[KS], wb[KS];
#pragma unroll
    for (int j = 0; j < KS; ++j) wa[j] = base[j];          // step s=0

#define H2(u) __builtin_bit_cast(h2, (u))
#define CONV_STEP(S, CUR)                                                     \
    {                                                                         \
        _Pragma("unroll")                                                     \
        for (int e = 0; e < 4; ++e) {                                         \
            int tl = (S) - e;                                                 \
            if (tl >= 0 && tl <= 6) {                                         \
                _Pragma("unroll")                                             \
                for (int vv = 0; vv < KS; ++vv)                               \
                    accL[tl] = __builtin_amdgcn_fdot2(H2(CUR[vv]),            \
                                   H2(dt[e * KS + vv]), accL[tl], false);     \
            }                                                                 \
            int th = (S) - 1 - e;                                             \
            if (th >= 0 && th <= 6) {                                         \
                _Pragma("unroll")                                             \
                for (int vv = 0; vv < KS; ++vv)                               \
                    accH[th] = __builtin_amdgcn_fdot2(H2(CUR[vv]),            \
                                   H2(ct[e * KS + vv]), accH[th], false);     \
            }                                                                 \
        }                                                                     \
    }

#pragma unroll
    for (int ss = 0; ss < 5; ++ss) {
        int s0 = 2 * ss, s1 = 2 * ss + 1;
        {
            const unsigned int* np = base + s1 * 64;
#pragma unroll
            for (int j = 0; j < KS; ++j) wb[j] = np[j];
        }
        CONV_STEP(s0, wa);
        {
            const unsigned int* np = base + (s0 + 2) * 64;
#pragma unroll
            for (int j = 0; j < KS; ++j) wa[j] = np[j];
        }
        CONV_STEP(s1, wb);
    }
    CONV_STEP(10, wa);
#undef CONV_STEP
#undef H2

    if (lane < WW) {
        float* ob = out + (size_t)bc * HW + (wid * 14) * WW + lane;
#pragma unroll
        for (int t = 0; t < 7; ++t) {
            ob[(2 * t) * WW]     = accL[t];
            ob[(2 * t + 1) * WW] = accH[t];
        }
    }
}

// ---------------------------------------------------------------------------
extern "C" void kernel_launch(void* const* d_in, const int* in_sizes, int n_in,
                              void* d_out, int out_size, void* d_ws, size_t ws_size,
                              hipStream_t stream) {
    const float* x    = (const float*)d_in[0];
    const float* ln0w = (const float*)d_in[1];
    const float* ln0b = (const float*)d_in[2];
    const float* w0   = (const float*)d_in[3];
    const float* ln1w = (const float*)d_in[4];
    const float* ln1b = (const float*)d_in[5];
    float* out = (float*)d_out;

    float*  p0     = (float*)d_ws;                     // [NCELL]
    float*  q1     = p0 + NCELL;                       // [NCELL]
    float2* part0c = (float2*)(q1 + NCELL);            // [NBC]
    float2* part1  = part0c + NBC;                     // [BB*MIDBLK]
    unsigned int* ktab = (unsigned int*)(part1 + BB * MIDBLK);   // [NBC*TABW]
    unsigned int* x16  = ktab + (size_t)NBC * TABW;    // [NBC*XP] = 48 MB

    pool_kernel<<<NBC / 4, 256, 0, stream>>>(x, p0, part0c, x16);
    mid_kernel <<<BB * MIDBLK, 512, 0, stream>>>(p0, ln0w, ln0b, w0, part0c, q1, part1);
    tab_kernel <<<NBC / 4, 256, 0, stream>>>(q1, part1, ln1w, ln1b, ktab);
    conv_kernel<<<NBC, 256, 0, stream>>>(x16, ktab, out);
}

// Round 22
// 66.533 us; speedup vs baseline: 1.0073x; 1.0073x over previous
//
#include <hip/hip_runtime.h>

// Problem constants (B,C,H,W,K) = (32,192,56,56,7)
#define BB 32
#define CC 192
#define HH 56
#define WW 56
#define KS 7
#define HW 3136        // 56*56
#define KK 49
#define CKK 9408       // C*K*K
#define NCELL (BB * CC * KK)   // 301056
#define NBC (BB * CC)          // 6144
#define MIDBLK 24              // mid blocks per sample
#define TABW 56                // u32 words per channel in tap table
#define XP 2048                // u32 words per channel in x16 (32 rowpairs x 64)

typedef _Float16 h2 __attribute__((ext_vector_type(2)));   // for fdot2 only

__device__ __forceinline__ unsigned int pack16(float a, float b) {
    return __builtin_bit_cast(unsigned int, __builtin_amdgcn_cvt_pkrtz(a, b));
}

// ---------------------------------------------------------------------------
// K1: WAVE-PER-CHANNEL pool + x16 emit, FLOAT4 loads.
// lane = c4 + 16*r (c4 0..13 col-quad, r 0..3 row-in-batch; c4 14,15 idle).
// Per 8-row group i, batch b: one float4 load/lane covers rows 8i+4b+0..3
// (896 contiguous bytes per wave). shfl_xor(16) pairs rows; even-r lanes
// pack 4 words + store one uint4 (words 4+4c4..7+4c4 of pr2 = 4i+2b+(r>>1)+2).
// Pool cells via shfl_xor 32/16/1; per-channel LN0 partial.
// ---------------------------------------------------------------------------
__global__ __launch_bounds__(256) void pool_kernel(const float* __restrict__ x,
                                                   float* __restrict__ p0,
                                                   float2* __restrict__ part0c,
                                                   unsigned int* __restrict__ x16) {
    int lane = threadIdx.x & 63;
    int bc   = blockIdx.x * 4 + (threadIdx.x >> 6);
    const float* src = x + (size_t)bc * HW;
    unsigned int* xp = x16 + (size_t)bc * XP;
    int c4 = lane & 15;
    int r  = lane >> 4;
    bool act = c4 < 14;

    float sv = 0.f, sq = 0.f;
#pragma unroll
    for (int i = 0; i < 7; ++i) {
        float si = 0.f;
#pragma unroll
        for (int b = 0; b < 2; ++b) {
            int row = 8 * i + 4 * b + r;
            float4 v = make_float4(0.f, 0.f, 0.f, 0.f);
            if (act) v = *(const float4*)(src + row * WW + 4 * c4);
            // partner row (r^1) for pairing
            float4 p;
            p.x = __shfl_xor(v.x, 16, 64);
            p.y = __shfl_xor(v.y, 16, 64);
            p.z = __shfl_xor(v.z, 16, 64);
            p.w = __shfl_xor(v.w, 16, 64);
            if (act && !(r & 1)) {
                int pr2 = 4 * i + 2 * b + (r >> 1) + 2;
                *(uint4*)(xp + pr2 * 64 + 4 + 4 * c4) =
                    make_uint4(pack16(v.x, p.x), pack16(v.y, p.y),
                               pack16(v.z, p.z), pack16(v.w, p.w));
            }
            si += v.x + v.y + v.z + v.w;
        }
        // sum over 8 rows (r-tree) then col pair -> 8x8 block sums
        si += __shfl_xor(si, 32, 64);
        si += __shfl_xor(si, 16, 64);
        si += __shfl_xor(si, 1, 64);
        if (r == 0 && (c4 & 1) == 0 && c4 < 14) {
            float pv = si * (1.f / 64.f);
            p0[(size_t)bc * KK + i * KS + (c4 >> 1)] = pv;
            sv += pv; sq += pv * pv;
        }
    }

    // ---- halo zeros: full rowpairs 0,1,30,31 + edge words of pr2 2..29 ----
    xp[0 * 64 + lane]  = 0u;
    xp[1 * 64 + lane]  = 0u;
    xp[30 * 64 + lane] = 0u;
    xp[31 * 64 + lane] = 0u;
#pragma unroll
    for (int t = 0; t < 4; ++t) {
        int idx = t * 64 + lane;                     // 0..255, need < 224
        if (idx < 224) {
            int pr2 = 2 + (idx >> 3);
            int j = idx & 7;
            xp[pr2 * 64 + (j < 4 ? j : 56 + j)] = 0u;
        }
    }

    // ---- per-channel LN0 partial (sv,sq nonzero only on cell lanes) ----
#pragma unroll
    for (int o = 32; o > 0; o >>= 1) {
        sv += __shfl_down(sv, o, 64);
        sq += __shfl_down(sq, o, 64);
    }
    if (lane == 0) part0c[bc] = make_float2(sv, sq);
}

// ---------------------------------------------------------------------------
// K2: LN0-normalize + depthwise 7x7 conv on the 7x7 map, one WAVE per (b,c).
// Stats0 from 192 per-channel partials (3 per lane, exact).
// ---------------------------------------------------------------------------
__global__ __launch_bounds__(512) void mid_kernel(
    const float* __restrict__ p0,
    const float* __restrict__ ln0w, const float* __restrict__ ln0b,
    const float* __restrict__ w0,
    const float2* __restrict__ part0c,
    float* __restrict__ q1,
    float2* __restrict__ part1)
{
    __shared__ float red[16];
    int tid  = threadIdx.x;
    int lane = tid & 63;
    int bc   = blockIdx.x * 8 + (tid >> 6);
    int b = bc / CC;
    int c = bc - b * CC;

    float s0 = 0.f, ss0 = 0.f;
#pragma unroll
    for (int t = 0; t < 3; ++t) {
        float2 p = part0c[b * CC + lane + 64 * t];   // 192 = 3*64 exact
        s0 += p.x; ss0 += p.y;
    }
#pragma unroll
    for (int o = 32; o > 0; o >>= 1) {
        s0  += __shfl_down(s0, o, 64);
        ss0 += __shfl_down(ss0, o, 64);
    }
    s0  = __shfl(s0, 0, 64);
    ss0 = __shfl(ss0, 0, 64);
    float mean = s0 * (1.f / CKK);
    float rstd = rsqrtf(ss0 * (1.f / CKK) - mean * mean + 1e-5f);

    float val = 0.f;
    if (lane < KK)
        val = (p0[(size_t)bc * KK + lane] - mean) * rstd * ln0w[c * KK + lane]
              + ln0b[c * KK + lane];

    int i0 = lane / KS;
    int j0 = lane - i0 * KS;
    const float* wc = w0 + c * KK;

    float acc = 0.f;
#pragma unroll
    for (int u = 0; u < KS; ++u) {
        int ii = i0 + u - 3;
#pragma unroll
        for (int v = 0; v < KS; ++v) {
            int jj = j0 + v - 3;
            bool ok = (ii >= 0) && (ii < KS) && (jj >= 0) && (jj < KS);
            int sl = ok ? (ii * KS + jj) : 0;
            float sv = __shfl(val, sl, 64);
            acc += ok ? sv * wc[u * KS + v] : 0.f;
        }
    }
    if (lane >= KK) acc = 0.f;
    if (lane < KK) q1[(size_t)bc * KK + lane] = acc;

    float s2 = acc, ss2 = acc * acc;
#pragma unroll
    for (int o = 32; o > 0; o >>= 1) {
        s2  += __shfl_down(s2, o, 64);
        ss2 += __shfl_down(ss2, o, 64);
    }
    if (lane == 0) {
        red[(tid >> 6) * 2 + 0] = s2;
        red[(tid >> 6) * 2 + 1] = ss2;
    }
    __syncthreads();
    if (tid == 0) {
        float a = 0.f, q = 0.f;
#pragma unroll
        for (int w = 0; w < 8; ++w) { a += red[2 * w]; q += red[2 * w + 1]; }
        part1[blockIdx.x] = make_float2(a, q);
    }
}

// ---------------------------------------------------------------------------
// K3: tab_kernel — LN1+ReLU taps -> NATURAL-PAIRING tap tables (1 wave/bc).
//   ktab[bc][0..27]  dt[e*7+v] = h2{ e>0 ? kt[2e-1][v] : 0, kt[2e][v] }
//   ktab[bc][28..55] ct[e*7+v] = h2{ kt[2e][v], e<3 ? kt[2e+1][v] : 0 }
// ---------------------------------------------------------------------------
__global__ __launch_bounds__(256) void tab_kernel(
    const float* __restrict__ q1, const float2* __restrict__ part1,
    const float* __restrict__ ln1w, const float* __restrict__ ln1b,
    unsigned int* __restrict__ ktab)
{
    int lane = threadIdx.x & 63;
    int bc   = blockIdx.x * 4 + (threadIdx.x >> 6);
    int b = bc / CC;
    int c = bc - b * CC;

    float s1 = 0.f, ss1 = 0.f;
    if (lane < MIDBLK) {
        float2 p = part1[b * MIDBLK + lane];
        s1 = p.x; ss1 = p.y;
    }
#pragma unroll
    for (int o = 32; o > 0; o >>= 1) {
        s1  += __shfl_down(s1, o, 64);
        ss1 += __shfl_down(ss1, o, 64);
    }
    s1  = __shfl(s1, 0, 64);
    ss1 = __shfl(ss1, 0, 64);
    float m = s1 * (1.f / CKK);
    float r = rsqrtf(ss1 * (1.f / CKK) - m * m + 1e-5f);

    float kt = 0.f;
    if (lane < KK) {
        float v = (q1[(size_t)bc * KK + lane] - m) * r * ln1w[c * KK + lane]
                  + ln1b[c * KK + lane];
        kt = v > 0.f ? v : 0.f;
    }

    bool isDt = lane < 28;
    int idx = isDt ? lane : (lane < TABW ? lane - 28 : 0);
    int e = idx / KS, v = idx - KS * e;
    int iA, iB; bool mA, mB;
    if (isDt) { mA = (e > 0); iA = mA ? (2 * e - 1) * KS + v : 0;
                mB = true;    iB = 2 * e * KS + v; }
    else      { mA = true;    iA = 2 * e * KS + v;
                mB = (e < 3); iB = mB ? (2 * e + 1) * KS + v : 0; }
    float va = __shfl(kt, iA, 64);
    float vb = __shfl(kt, iB, 64);
    unsigned int w = pack16(mA ? va : 0.f, mB ? vb : 0.f);
    if (lane < TABW)
        ktab[(size_t)bc * TABW + lane] = w;
}

// ---------------------------------------------------------------------------
// K4: per-(b,c) depthwise 7x7 SAME conv — NO LDS, NO BARRIER (R20-verified).
// Reads pre-packed x16 directly; lane owns output col; 392 dot2/wave.
// ---------------------------------------------------------------------------
__global__ __launch_bounds__(256) void conv_kernel(
    const unsigned int* __restrict__ x16,
    const unsigned int* __restrict__ ktab,
    float* __restrict__ out)
{
    int bc   = blockIdx.x;
    int tid  = threadIdx.x;
    int lane = tid & 63;
    int wid  = tid >> 6;

    // ---- tap tables (block-uniform -> s_load / SGPRs) ----
    const uint4* tb = (const uint4*)(ktab + (size_t)bc * TABW);
    unsigned int dt[28], ct[28];
#pragma unroll
    for (int i = 0; i < 7; ++i) {
        uint4 t4 = tb[i];
        dt[4 * i + 0] = t4.x; dt[4 * i + 1] = t4.y;
        dt[4 * i + 2] = t4.z; dt[4 * i + 3] = t4.w;
    }
#pragma unroll
    for (int i = 0; i < 7; ++i) {
        uint4 t4 = tb[7 + i];
        ct[4 * i + 0] = t4.x; ct[4 * i + 1] = t4.y;
        ct[4 * i + 2] = t4.z; ct[4 * i + 3] = t4.w;
    }

    int ll = lane < 56 ? lane : 55;      // clamp: lanes 56-63 duplicate lane 55
    const unsigned int* base = x16 + (size_t)bc * XP + (wid * 7) * 64 + ll + 1;

    float accL[7], accH[7];
#pragma unroll
    for (int t = 0; t < 7; ++t) { accL[t] = 0.f; accH[t] = 0.f; }

    unsigned int wa[KS], wb[KS];
#pragma unroll
    for (int j = 0; j < KS; ++j) wa[j] = base[j];          // step s=0

#define H2(u) __builtin_bit_cast(h2, (u))
#define CONV_STEP(S, CUR)                                                     \
    {                                                                         \
        _Pragma("unroll")                                                     \
        for (int e = 0; e < 4; ++e) {                                         \
            int tl = (S) - e;                                                 \
            if (tl >= 0 && tl <= 6) {                                         \
                _Pragma("unroll")                                             \
                for (int vv = 0; vv < KS; ++vv)                               \
                    accL[tl] = __builtin_amdgcn_fdot2(H2(CUR[vv]),            \
                                   H2(dt[e * KS + vv]), accL[tl], false);     \
            }                                                                 \
            int th = (S) - 1 - e;                                             \
            if (th >= 0 && th <= 6) {                                         \
                _Pragma("unroll")                                             \
                for (int vv = 0; vv < KS; ++vv)                               \
                    accH[th] = __builtin_amdgcn_fdot2(H2(CUR[vv]),            \
                                   H2(ct[e * KS + vv]), accH[th], false);     \
            }                                                                 \
        }                                                                     \
    }

#pragma unroll
    for (int ss = 0; ss < 5; ++ss) {
        int s0 = 2 * ss, s1 = 2 * ss + 1;
        {
            const unsigned int* np = base + s1 * 64;
#pragma unroll
            for (int j = 0; j < KS; ++j) wb[j] = np[j];
        }
        CONV_STEP(s0, wa);
        {
            const unsigned int* np = base + (s0 + 2) * 64;
#pragma unroll
            for (int j = 0; j < KS; ++j) wa[j] = np[j];
        }
        CONV_STEP(s1, wb);
    }
    CONV_STEP(10, wa);
#undef CONV_STEP
#undef H2

    if (lane < WW) {
        float* ob = out + (size_t)bc * HW + (wid * 14) * WW + lane;
#pragma unroll
        for (int t = 0; t < 7; ++t) {
            ob[(2 * t) * WW]     = accL[t];
            ob[(2 * t + 1) * WW] = accH[t];
        }
    }
}

// ---------------------------------------------------------------------------
extern "C" void kernel_launch(void* const* d_in, const int* in_sizes, int n_in,
                              void* d_out, int out_size, void* d_ws, size_t ws_size,
                              hipStream_t stream) {
    const float* x    = (const float*)d_in[0];
    const float* ln0w = (const float*)d_in[1];
    const float* ln0b = (const float*)d_in[2];
    const float* w0   = (const float*)d_in[3];
    const float* ln1w = (const float*)d_in[4];
    const float* ln1b = (const float*)d_in[5];
    float* out = (float*)d_out;

    float*  p0     = (float*)d_ws;                     // [NCELL]
    float*  q1     = p0 + NCELL;                       // [NCELL]
    float2* part0c = (float2*)(q1 + NCELL);            // [NBC]
    float2* part1  = part0c + NBC;                     // [BB*MIDBLK]
    unsigned int* ktab = (unsigned int*)(part1 + BB * MIDBLK);   // [NBC*TABW]
    unsigned int* x16  = ktab + (size_t)NBC * TABW;    // [NBC*XP] = 48 MB

    pool_kernel<<<NBC / 4, 256, 0, stream>>>(x, p0, part0c, x16);
    mid_kernel <<<BB * MIDBLK, 512, 0, stream>>>(p0, ln0w, ln0b, w0, part0c, q1, part1);
    tab_kernel <<<NBC / 4, 256, 0, stream>>>(q1, part1, ln1w, ln1b, ktab);
    conv_kernel<<<NBC, 256, 0, stream>>>(x16, ktab, out);
}

// Round 23
// 65.565 us; speedup vs baseline: 1.0222x; 1.0148x over previous
//
#include <hip/hip_runtime.h>

// Problem constants (B,C,H,W,K) = (32,192,56,56,7)
#define BB 32
#define CC 192
#define HH 56
#define WW 56
#define KS 7
#define HW 3136        // 56*56
#define KK 49
#define CKK 9408       // C*K*K
#define NCELL (BB * CC * KK)   // 301056
#define NBC (BB * CC)          // 6144
#define MIDBLK 24              // mid blocks per sample
#define TABW 56                // u32 words per channel in tap table
#define XP 2048                // u32 words per channel in x16 (32 rowpairs x 64)

typedef _Float16 h2 __attribute__((ext_vector_type(2)));   // for fdot2 only

__device__ __forceinline__ unsigned int pack16(float a, float b) {
    return __builtin_bit_cast(unsigned int, __builtin_amdgcn_cvt_pkrtz(a, b));
}

// ---------------------------------------------------------------------------
// K1: WAVE-PER-CHANNEL pool + x16 emit — ALL LOADS UPFRONT, NO PACK SHUFFLES.
// lane = rp*16 + c4 (rp 0..3 rowpair-in-group, c4 0..13 col-quad; c4 14,15
// idle with clamped addresses). Upfront: ld[7][2] float4 = 14 independent
// loads (full MLP). Per group i: lane packs its rowpair {8i+2rp, 8i+2rp+1}
// into 4 words -> one coalesced uint4 store at pr2 = 4i+rp+2 (natural
// pairing, matches tab/conv); pool sums via 3 scalar shfl_xor (32/16/1).
// ---------------------------------------------------------------------------
__global__ __launch_bounds__(256) void pool_kernel(const float* __restrict__ x,
                                                   float* __restrict__ p0,
                                                   float2* __restrict__ part0c,
                                                   unsigned int* __restrict__ x16) {
    int lane = threadIdx.x & 63;
    int bc   = blockIdx.x * 4 + (threadIdx.x >> 6);
    const float* src = x + (size_t)bc * HW;
    unsigned int* xp = x16 + (size_t)bc * XP;
    int c4 = lane & 15;
    int rp = lane >> 4;
    bool act = c4 < 14;
    int cc = act ? c4 : 13;                      // clamp: garbage isolated

    // ---- all 14 loads upfront (independent -> deep MLP) ----
    float4 ld[7][2];
#pragma unroll
    for (int i = 0; i < 7; ++i) {
        ld[i][0] = *(const float4*)(src + (8 * i + 2 * rp) * WW + 4 * cc);
        ld[i][1] = *(const float4*)(src + (8 * i + 2 * rp + 1) * WW + 4 * cc);
    }

    float sv = 0.f, sq = 0.f;
#pragma unroll
    for (int i = 0; i < 7; ++i) {
        float4 a = ld[i][0], b = ld[i][1];
        if (act) {
            *(uint4*)(xp + (4 * i + rp + 2) * 64 + 4 + 4 * c4) =
                make_uint4(pack16(a.x, b.x), pack16(a.y, b.y),
                           pack16(a.z, b.z), pack16(a.w, b.w));
        }
        float si = ((a.x + a.y) + (a.z + a.w)) + ((b.x + b.y) + (b.z + b.w));
        si += __shfl_xor(si, 32, 64);            // rp 0<->2, 1<->3
        si += __shfl_xor(si, 16, 64);            // rp 0<->1 -> all 8 rows
        si += __shfl_xor(si, 1, 64);             // col-quad pair -> 8 cols
        if (act && (c4 & 1) == 0 && rp == 0) {
            float pv = si * (1.f / 64.f);
            p0[(size_t)bc * KK + i * KS + (c4 >> 1)] = pv;
            sv += pv; sq += pv * pv;
        }
    }

    // ---- halo zeros: full rowpairs 0,1,30,31 + edge words of pr2 2..29 ----
    xp[0 * 64 + lane]  = 0u;
    xp[1 * 64 + lane]  = 0u;
    xp[30 * 64 + lane] = 0u;
    xp[31 * 64 + lane] = 0u;
#pragma unroll
    for (int t = 0; t < 4; ++t) {
        int idx = t * 64 + lane;                 // 0..255, need < 224
        if (idx < 224) {
            int pr2 = 2 + (idx >> 3);
            int j = idx & 7;
            xp[pr2 * 64 + (j < 4 ? j : 56 + j)] = 0u;
        }
    }

    // ---- per-channel LN0 partial (sv,sq nonzero only on cell lanes) ----
#pragma unroll
    for (int o = 32; o > 0; o >>= 1) {
        sv += __shfl_down(sv, o, 64);
        sq += __shfl_down(sq, o, 64);
    }
    if (lane == 0) part0c[bc] = make_float2(sv, sq);
}

// ---------------------------------------------------------------------------
// K2: LN0-normalize + depthwise 7x7 conv on the 7x7 map, one WAVE per (b,c).
// Stats0 from 192 per-channel partials (3 per lane, exact).
// ---------------------------------------------------------------------------
__global__ __launch_bounds__(512) void mid_kernel(
    const float* __restrict__ p0,
    const float* __restrict__ ln0w, const float* __restrict__ ln0b,
    const float* __restrict__ w0,
    const float2* __restrict__ part0c,
    float* __restrict__ q1,
    float2* __restrict__ part1)
{
    __shared__ float red[16];
    int tid  = threadIdx.x;
    int lane = tid & 63;
    int bc   = blockIdx.x * 8 + (tid >> 6);
    int b = bc / CC;
    int c = bc - b * CC;

    float s0 = 0.f, ss0 = 0.f;
#pragma unroll
    for (int t = 0; t < 3; ++t) {
        float2 p = part0c[b * CC + lane + 64 * t];   // 192 = 3*64 exact
        s0 += p.x; ss0 += p.y;
    }
#pragma unroll
    for (int o = 32; o > 0; o >>= 1) {
        s0  += __shfl_down(s0, o, 64);
        ss0 += __shfl_down(ss0, o, 64);
    }
    s0  = __shfl(s0, 0, 64);
    ss0 = __shfl(ss0, 0, 64);
    float mean = s0 * (1.f / CKK);
    float rstd = rsqrtf(ss0 * (1.f / CKK) - mean * mean + 1e-5f);

    float val = 0.f;
    if (lane < KK)
        val = (p0[(size_t)bc * KK + lane] - mean) * rstd * ln0w[c * KK + lane]
              + ln0b[c * KK + lane];

    int i0 = lane / KS;
    int j0 = lane - i0 * KS;
    const float* wc = w0 + c * KK;

    float acc = 0.f;
#pragma unroll
    for (int u = 0; u < KS; ++u) {
        int ii = i0 + u - 3;
#pragma unroll
        for (int v = 0; v < KS; ++v) {
            int jj = j0 + v - 3;
            bool ok = (ii >= 0) && (ii < KS) && (jj >= 0) && (jj < KS);
            int sl = ok ? (ii * KS + jj) : 0;
            float sv = __shfl(val, sl, 64);
            acc += ok ? sv * wc[u * KS + v] : 0.f;
        }
    }
    if (lane >= KK) acc = 0.f;
    if (lane < KK) q1[(size_t)bc * KK + lane] = acc;

    float s2 = acc, ss2 = acc * acc;
#pragma unroll
    for (int o = 32; o > 0; o >>= 1) {
        s2  += __shfl_down(s2, o, 64);
        ss2 += __shfl_down(ss2, o, 64);
    }
    if (lane == 0) {
        red[(tid >> 6) * 2 + 0] = s2;
        red[(tid >> 6) * 2 + 1] = ss2;
    }
    __syncthreads();
    if (tid == 0) {
        float a = 0.f, q = 0.f;
#pragma unroll
        for (int w = 0; w < 8; ++w) { a += red[2 * w]; q += red[2 * w + 1]; }
        part1[blockIdx.x] = make_float2(a, q);
    }
}

// ---------------------------------------------------------------------------
// K3: tab_kernel — LN1+ReLU taps -> NATURAL-PAIRING tap tables (1 wave/bc).
//   ktab[bc][0..27]  dt[e*7+v] = h2{ e>0 ? kt[2e-1][v] : 0, kt[2e][v] }
//   ktab[bc][28..55] ct[e*7+v] = h2{ kt[2e][v], e<3 ? kt[2e+1][v] : 0 }
// ---------------------------------------------------------------------------
__global__ __launch_bounds__(256) void tab_kernel(
    const float* __restrict__ q1, const float2* __restrict__ part1,
    const float* __restrict__ ln1w, const float* __restrict__ ln1b,
    unsigned int* __restrict__ ktab)
{
    int lane = threadIdx.x & 63;
    int bc   = blockIdx.x * 4 + (threadIdx.x >> 6);
    int b = bc / CC;
    int c = bc - b * CC;

    float s1 = 0.f, ss1 = 0.f;
    if (lane < MIDBLK) {
        float2 p = part1[b * MIDBLK + lane];
        s1 = p.x; ss1 = p.y;
    }
#pragma unroll
    for (int o = 32; o > 0; o >>= 1) {
        s1  += __shfl_down(s1, o, 64);
        ss1 += __shfl_down(ss1, o, 64);
    }
    s1  = __shfl(s1, 0, 64);
    ss1 = __shfl(ss1, 0, 64);
    float m = s1 * (1.f / CKK);
    float r = rsqrtf(ss1 * (1.f / CKK) - m * m + 1e-5f);

    float kt = 0.f;
    if (lane < KK) {
        float v = (q1[(size_t)bc * KK + lane] - m) * r * ln1w[c * KK + lane]
                  + ln1b[c * KK + lane];
        kt = v > 0.f ? v : 0.f;
    }

    bool isDt = lane < 28;
    int idx = isDt ? lane : (lane < TABW ? lane - 28 : 0);
    int e = idx / KS, v = idx - KS * e;
    int iA, iB; bool mA, mB;
    if (isDt) { mA = (e > 0); iA = mA ? (2 * e - 1) * KS + v : 0;
                mB = true;    iB = 2 * e * KS + v; }
    else      { mA = true;    iA = 2 * e * KS + v;
                mB = (e < 3); iB = mB ? (2 * e + 1) * KS + v : 0; }
    float va = __shfl(kt, iA, 64);
    float vb = __shfl(kt, iB, 64);
    unsigned int w = pack16(mA ? va : 0.f, mB ? vb : 0.f);
    if (lane < TABW)
        ktab[(size_t)bc * TABW + lane] = w;
}

// ---------------------------------------------------------------------------
// K4: per-(b,c) depthwise 7x7 SAME conv — NO LDS, NO BARRIER (R20-verified).
// Reads pre-packed x16 directly; lane owns output col; 392 dot2/wave.
// ---------------------------------------------------------------------------
__global__ __launch_bounds__(256) void conv_kernel(
    const unsigned int* __restrict__ x16,
    const unsigned int* __restrict__ ktab,
    float* __restrict__ out)
{
    int bc   = blockIdx.x;
    int tid  = threadIdx.x;
    int lane = tid & 63;
    int wid  = tid >> 6;

    // ---- tap tables (block-uniform -> s_load / SGPRs) ----
    const uint4* tb = (const uint4*)(ktab + (size_t)bc * TABW);
    unsigned int dt[28], ct[28];
#pragma unroll
    for (int i = 0; i < 7; ++i) {
        uint4 t4 = tb[i];
        dt[4 * i + 0] = t4.x; dt[4 * i + 1] = t4.y;
        dt[4 * i + 2] = t4.z; dt[4 * i + 3] = t4.w;
    }
#pragma unroll
    for (int i = 0; i < 7; ++i) {
        uint4 t4 = tb[7 + i];
        ct[4 * i + 0] = t4.x; ct[4 * i + 1] = t4.y;
        ct[4 * i + 2] = t4.z; ct[4 * i + 3] = t4.w;
    }

    int ll = lane < 56 ? lane : 55;      // clamp: lanes 56-63 duplicate lane 55
    const unsigned int* base = x16 + (size_t)bc * XP + (wid * 7) * 64 + ll + 1;

    float accL[7], accH[7];
#pragma unroll
    for (int t = 0; t < 7; ++t) { accL[t] = 0.f; accH[t] = 0.f; }

    unsigned int wa[KS], wb[KS];
#pragma unroll
    for (int j = 0; j < KS; ++j) wa[j] = base[j];          // step s=0

#define H2(u) __builtin_bit_cast(h2, (u))
#define CONV_STEP(S, CUR)                                                     \
    {                                                                         \
        _Pragma("unroll")                                                     \
        for (int e = 0; e < 4; ++e) {                                         \
            int tl = (S) - e;                                                 \
            if (tl >= 0 && tl <= 6) {                                         \
                _Pragma("unroll")                                             \
                for (int vv = 0; vv < KS; ++vv)                               \
                    accL[tl] = __builtin_amdgcn_fdot2(H2(CUR[vv]),            \
                                   H2(dt[e * KS + vv]), accL[tl], false);     \
            }                                                                 \
            int th = (S) - 1 - e;                                             \
            if (th >= 0 && th <= 6) {                                         \
                _Pragma("unroll")                                             \
                for (int vv = 0; vv < KS; ++vv)                               \
                    accH[th] = __builtin_amdgcn_fdot2(H2(CUR[vv]),            \
                                   H2(ct[e * KS + vv]), accH[th], false);     \
            }                                                                 \
        }                                                                     \
    }

#pragma unroll
    for (int ss = 0; ss < 5; ++ss) {
        int s0 = 2 * ss, s1 = 2 * ss + 1;
        {
            const unsigned int* np = base + s1 * 64;
#pragma unroll
            for (int j = 0; j < KS; ++j) wb[j] = np[j];
        }
        CONV_STEP(s0, wa);
        {
            const unsigned int* np = base + (s0 + 2) * 64;
#pragma unroll
            for (int j = 0; j < KS; ++j) wa[j] = np[j];
        }
        CONV_STEP(s1, wb);
    }
    CONV_STEP(10, wa);
#undef CONV_STEP
#undef H2

    if (lane < WW) {
        float* ob = out + (size_t)bc * HW + (wid * 14) * WW + lane;
#pragma unroll
        for (int t = 0; t < 7; ++t) {
            ob[(2 * t) * WW]     = accL[t];
            ob[(2 * t + 1) * WW] = accH[t];
        }
    }
}

// ---------------------------------------------------------------------------
extern "C" void kernel_launch(void* const* d_in, const int* in_sizes, int n_in,
                              void* d_out, int out_size, void* d_ws, size_t ws_size,
                              hipStream_t stream) {
    const float* x    = (const float*)d_in[0];
    const float* ln0w = (const float*)d_in[1];
    const float* ln0b = (const float*)d_in[2];
    const float* w0   = (const float*)d_in[3];
    const float* ln1w = (const float*)d_in[4];
    const float* ln1b = (const float*)d_in[5];
    float* out = (float*)d_out;

    float*  p0     = (float*)d_ws;                     // [NCELL]
    float*  q1     = p0 + NCELL;                       // [NCELL]
    float2* part0c = (float2*)(q1 + NCELL);            // [NBC]
    float2* part1  = part0c + NBC;                     // [BB*MIDBLK]
    unsigned int* ktab = (unsigned int*)(part1 + BB * MIDBLK);   // [NBC*TABW]
    unsigned int* x16  = ktab + (size_t)NBC * TABW;    // [NBC*XP] = 48 MB

    pool_kernel<<<NBC / 4, 256, 0, stream>>>(x, p0, part0c, x16);
    mid_kernel <<<BB * MIDBLK, 512, 0, stream>>>(p0, ln0w, ln0b, w0, part0c, q1, part1);
    tab_kernel <<<NBC / 4, 256, 0, stream>>>(q1, part1, ln1w, ln1b, ktab);
    conv_kernel<<<NBC, 256, 0, stream>>>(x16, ktab, out);
}

// Round 24
// 65.473 us; speedup vs baseline: 1.0236x; 1.0014x over previous
//
#include <hip/hip_runtime.h>

// Problem constants (B,C,H,W,K) = (32,192,56,56,7)
#define BB 32
#define CC 192
#define HH 56
#define WW 56
#define KS 7
#define HW 3136        // 56*56
#define KK 49
#define CKK 9408       // C*K*K
#define NCELL (BB * CC * KK)   // 301056
#define NBC (BB * CC)          // 6144
#define MIDBLK 24              // mid blocks per sample
#define TABW 56                // u32 words per channel in tap table
#define XP 2048                // u32 words per channel in x16 (32 rowpairs x 64)

typedef _Float16 h2 __attribute__((ext_vector_type(2)));   // for fdot2 only

__device__ __forceinline__ unsigned int pack16(float a, float b) {
    return __builtin_bit_cast(unsigned int, __builtin_amdgcn_cvt_pkrtz(a, b));
}

// ---------------------------------------------------------------------------
// K1: WAVE-PER-CHANNEL pool + x16 emit — loads PINNED upfront via
// sched_barrier(0) (R23's compiler sank them; VGPR 40 -> ~85 now).
// lane = rp*16 + c4. Halo edges now 2 aligned uint4 stores per row.
// ---------------------------------------------------------------------------
__global__ __launch_bounds__(256) void pool_kernel(const float* __restrict__ x,
                                                   float* __restrict__ p0,
                                                   float2* __restrict__ part0c,
                                                   unsigned int* __restrict__ x16) {
    int lane = threadIdx.x & 63;
    int bc   = blockIdx.x * 4 + (threadIdx.x >> 6);
    const float* src = x + (size_t)bc * HW;
    unsigned int* xp = x16 + (size_t)bc * XP;
    int c4 = lane & 15;
    int rp = lane >> 4;
    bool act = c4 < 14;
    int cc = act ? c4 : 13;                      // clamp: garbage isolated

    // ---- all 14 loads upfront; sched_barrier pins them before any use ----
    float4 ld[7][2];
#pragma unroll
    for (int i = 0; i < 7; ++i) {
        ld[i][0] = *(const float4*)(src + (8 * i + 2 * rp) * WW + 4 * cc);
        ld[i][1] = *(const float4*)(src + (8 * i + 2 * rp + 1) * WW + 4 * cc);
    }
    __builtin_amdgcn_sched_barrier(0);           // force all loads in flight

    float sv = 0.f, sq = 0.f;
#pragma unroll
    for (int i = 0; i < 7; ++i) {
        float4 a = ld[i][0], b = ld[i][1];
        if (act) {
            *(uint4*)(xp + (4 * i + rp + 2) * 64 + 4 + 4 * c4) =
                make_uint4(pack16(a.x, b.x), pack16(a.y, b.y),
                           pack16(a.z, b.z), pack16(a.w, b.w));
        }
        float si = ((a.x + a.y) + (a.z + a.w)) + ((b.x + b.y) + (b.z + b.w));
        si += __shfl_xor(si, 32, 64);            // rp 0<->2, 1<->3
        si += __shfl_xor(si, 16, 64);            // rp 0<->1 -> all 8 rows
        si += __shfl_xor(si, 1, 64);             // col-quad pair -> 8 cols
        if (act && (c4 & 1) == 0 && rp == 0) {
            float pv = si * (1.f / 64.f);
            p0[(size_t)bc * KK + i * KS + (c4 >> 1)] = pv;
            sv += pv; sq += pv * pv;
        }
    }

    // ---- halo zeros: full rowpairs 0,1,30,31 + edge uint4s of pr2 2..29 ----
    xp[0 * 64 + lane]  = 0u;
    xp[1 * 64 + lane]  = 0u;
    xp[30 * 64 + lane] = 0u;
    xp[31 * 64 + lane] = 0u;
    if (lane < 56) {                             // 28 rows x 2 sides
        int pr2 = 2 + (lane >> 1);
        int side = lane & 1;                     // 0: words 0-3, 1: words 60-63
        *(uint4*)(xp + pr2 * 64 + side * 60) = make_uint4(0u, 0u, 0u, 0u);
    }

    // ---- per-channel LN0 partial (sv,sq nonzero only on cell lanes) ----
#pragma unroll
    for (int o = 32; o > 0; o >>= 1) {
        sv += __shfl_down(sv, o, 64);
        sq += __shfl_down(sq, o, 64);
    }
    if (lane == 0) part0c[bc] = make_float2(sv, sq);
}

// ---------------------------------------------------------------------------
// K2: LN0-normalize + depthwise 7x7 conv on the 7x7 map, one WAVE per (b,c).
// Stats0 from 192 per-channel partials (3 per lane, exact).
// ---------------------------------------------------------------------------
__global__ __launch_bounds__(512) void mid_kernel(
    const float* __restrict__ p0,
    const float* __restrict__ ln0w, const float* __restrict__ ln0b,
    const float* __restrict__ w0,
    const float2* __restrict__ part0c,
    float* __restrict__ q1,
    float2* __restrict__ part1)
{
    __shared__ float red[16];
    int tid  = threadIdx.x;
    int lane = tid & 63;
    int bc   = blockIdx.x * 8 + (tid >> 6);
    int b = bc / CC;
    int c = bc - b * CC;

    float s0 = 0.f, ss0 = 0.f;
#pragma unroll
    for (int t = 0; t < 3; ++t) {
        float2 p = part0c[b * CC + lane + 64 * t];   // 192 = 3*64 exact
        s0 += p.x; ss0 += p.y;
    }
#pragma unroll
    for (int o = 32; o > 0; o >>= 1) {
        s0  += __shfl_down(s0, o, 64);
        ss0 += __shfl_down(ss0, o, 64);
    }
    s0  = __shfl(s0, 0, 64);
    ss0 = __shfl(ss0, 0, 64);
    float mean = s0 * (1.f / CKK);
    float rstd = rsqrtf(ss0 * (1.f / CKK) - mean * mean + 1e-5f);

    float val = 0.f;
    if (lane < KK)
        val = (p0[(size_t)bc * KK + lane] - mean) * rstd * ln0w[c * KK + lane]
              + ln0b[c * KK + lane];

    int i0 = lane / KS;
    int j0 = lane - i0 * KS;
    const float* wc = w0 + c * KK;

    float acc = 0.f;
#pragma unroll
    for (int u = 0; u < KS; ++u) {
        int ii = i0 + u - 3;
#pragma unroll
        for (int v = 0; v < KS; ++v) {
            int jj = j0 + v - 3;
            bool ok = (ii >= 0) && (ii < KS) && (jj >= 0) && (jj < KS);
            int sl = ok ? (ii * KS + jj) : 0;
            float sv = __shfl(val, sl, 64);
            acc += ok ? sv * wc[u * KS + v] : 0.f;
        }
    }
    if (lane >= KK) acc = 0.f;
    if (lane < KK) q1[(size_t)bc * KK + lane] = acc;

    float s2 = acc, ss2 = acc * acc;
#pragma unroll
    for (int o = 32; o > 0; o >>= 1) {
        s2  += __shfl_down(s2, o, 64);
        ss2 += __shfl_down(ss2, o, 64);
    }
    if (lane == 0) {
        red[(tid >> 6) * 2 + 0] = s2;
        red[(tid >> 6) * 2 + 1] = ss2;
    }
    __syncthreads();
    if (tid == 0) {
        float a = 0.f, q = 0.f;
#pragma unroll
        for (int w = 0; w < 8; ++w) { a += red[2 * w]; q += red[2 * w + 1]; }
        part1[blockIdx.x] = make_float2(a, q);
    }
}

// ---------------------------------------------------------------------------
// K3: tab_kernel — LN1+ReLU taps -> NATURAL-PAIRING tap tables (1 wave/bc).
//   ktab[bc][0..27]  dt[e*7+v] = h2{ e>0 ? kt[2e-1][v] : 0, kt[2e][v] }
//   ktab[bc][28..55] ct[e*7+v] = h2{ kt[2e][v], e<3 ? kt[2e+1][v] : 0 }
// ---------------------------------------------------------------------------
__global__ __launch_bounds__(256) void tab_kernel(
    const float* __restrict__ q1, const float2* __restrict__ part1,
    const float* __restrict__ ln1w, const float* __restrict__ ln1b,
    unsigned int* __restrict__ ktab)
{
    int lane = threadIdx.x & 63;
    int bc   = blockIdx.x * 4 + (threadIdx.x >> 6);
    int b = bc / CC;
    int c = bc - b * CC;

    float s1 = 0.f, ss1 = 0.f;
    if (lane < MIDBLK) {
        float2 p = part1[b * MIDBLK + lane];
        s1 = p.x; ss1 = p.y;
    }
#pragma unroll
    for (int o = 32; o > 0; o >>= 1) {
        s1  += __shfl_down(s1, o, 64);
        ss1 += __shfl_down(ss1, o, 64);
    }
    s1  = __shfl(s1, 0, 64);
    ss1 = __shfl(ss1, 0, 64);
    float m = s1 * (1.f / CKK);
    float r = rsqrtf(ss1 * (1.f / CKK) - m * m + 1e-5f);

    float kt = 0.f;
    if (lane < KK) {
        float v = (q1[(size_t)bc * KK + lane] - m) * r * ln1w[c * KK + lane]
                  + ln1b[c * KK + lane];
        kt = v > 0.f ? v : 0.f;
    }

    bool isDt = lane < 28;
    int idx = isDt ? lane : (lane < TABW ? lane - 28 : 0);
    int e = idx / KS, v = idx - KS * e;
    int iA, iB; bool mA, mB;
    if (isDt) { mA = (e > 0); iA = mA ? (2 * e - 1) * KS + v : 0;
                mB = true;    iB = 2 * e * KS + v; }
    else      { mA = true;    iA = 2 * e * KS + v;
                mB = (e < 3); iB = mB ? (2 * e + 1) * KS + v : 0; }
    float va = __shfl(kt, iA, 64);
    float vb = __shfl(kt, iB, 64);
    unsigned int w = pack16(mA ? va : 0.f, mB ? vb : 0.f);
    if (lane < TABW)
        ktab[(size_t)bc * TABW + lane] = w;
}

// ---------------------------------------------------------------------------
// K4: per-(b,c) depthwise 7x7 SAME conv — NO LDS, NO BARRIER (R20-verified).
// Reads pre-packed x16 directly; lane owns output col; 392 dot2/wave.
// ---------------------------------------------------------------------------
__global__ __launch_bounds__(256) void conv_kernel(
    const unsigned int* __restrict__ x16,
    const unsigned int* __restrict__ ktab,
    float* __restrict__ out)
{
    int bc   = blockIdx.x;
    int tid  = threadIdx.x;
    int lane = tid & 63;
    int wid  = tid >> 6;

    // ---- tap tables (block-uniform -> s_load / SGPRs) ----
    const uint4* tb = (const uint4*)(ktab + (size_t)bc * TABW);
    unsigned int dt[28], ct[28];
#pragma unroll
    for (int i = 0; i < 7; ++i) {
        uint4 t4 = tb[i];
        dt[4 * i + 0] = t4.x; dt[4 * i + 1] = t4.y;
        dt[4 * i + 2] = t4.z; dt[4 * i + 3] = t4.w;
    }
#pragma unroll
    for (int i = 0; i < 7; ++i) {
        uint4 t4 = tb[7 + i];
        ct[4 * i + 0] = t4.x; ct[4 * i + 1] = t4.y;
        ct[4 * i + 2] = t4.z; ct[4 * i + 3] = t4.w;
    }

    int ll = lane < 56 ? lane : 55;      // clamp: lanes 56-63 duplicate lane 55
    const unsigned int* base = x16 + (size_t)bc * XP + (wid * 7) * 64 + ll + 1;

    float accL[7], accH[7];
#pragma unroll
    for (int t = 0; t < 7; ++t) { accL[t] = 0.f; accH[t] = 0.f; }

    unsigned int wa[KS], wb[KS];
#pragma unroll
    for (int j = 0; j < KS; ++j) wa[j] = base[j];          // step s=0

#define H2(u) __builtin_bit_cast(h2, (u))
#define CONV_STEP(S, CUR)                                                     \
    {                                                                         \
        _Pragma("unroll")                                                     \
        for (int e = 0; e < 4; ++e) {                                         \
            int tl = (S) - e;                                                 \
            if (tl >= 0 && tl <= 6) {                                         \
                _Pragma("unroll")                                             \
                for (int vv = 0; vv < KS; ++vv)                               \
                    accL[tl] = __builtin_amdgcn_fdot2(H2(CUR[vv]),            \
                                   H2(dt[e * KS + vv]), accL[tl], false);     \
            }                                                                 \
            int th = (S) - 1 - e;                                             \
            if (th >= 0 && th <= 6) {                                         \
                _Pragma("unroll")                                             \
                for (int vv = 0; vv < KS; ++vv)                               \
                    accH[th] = __builtin_amdgcn_fdot2(H2(CUR[vv]),            \
                                   H2(ct[e * KS + vv]), accH[th], false);     \
            }                                                                 \
        }                                                                     \
    }

#pragma unroll
    for (int ss = 0; ss < 5; ++ss) {
        int s0 = 2 * ss, s1 = 2 * ss + 1;
        {
            const unsigned int* np = base + s1 * 64;
#pragma unroll
            for (int j = 0; j < KS; ++j) wb[j] = np[j];
        }
        CONV_STEP(s0, wa);
        {
            const unsigned int* np = base + (s0 + 2) * 64;
#pragma unroll
            for (int j = 0; j < KS; ++j) wa[j] = np[j];
        }
        CONV_STEP(s1, wb);
    }
    CONV_STEP(10, wa);
#undef CONV_STEP
#undef H2

    if (lane < WW) {
        float* ob = out + (size_t)bc * HW + (wid * 14) * WW + lane;
#pragma unroll
        for (int t = 0; t < 7; ++t) {
            ob[(2 * t) * WW]     = accL[t];
            ob[(2 * t + 1) * WW] = accH[t];
        }
    }
}

// ---------------------------------------------------------------------------
extern "C" void kernel_launch(void* const* d_in, const int* in_sizes, int n_in,
                              void* d_out, int out_size, void* d_ws, size_t ws_size,
                              hipStream_t stream) {
    const float* x    = (const float*)d_in[0];
    const float* ln0w = (const float*)d_in[1];
    const float* ln0b = (const float*)d_in[2];
    const float* w0   = (const float*)d_in[3];
    const float* ln1w = (const float*)d_in[4];
    const float* ln1b = (const float*)d_in[5];
    float* out = (float*)d_out;

    float*  p0     = (float*)d_ws;                     // [NCELL]
    float*  q1     = p0 + NCELL;                       // [NCELL]
    float2* part0c = (float2*)(q1 + NCELL);            // [NBC]
    float2* part1  = part0c + NBC;                     // [BB*MIDBLK]
    unsigned int* ktab = (unsigned int*)(part1 + BB * MIDBLK);   // [NBC*TABW]
    unsigned int* x16  = ktab + (size_t)NBC * TABW;    // [NBC*XP] = 48 MB

    pool_kernel<<<NBC / 4, 256, 0, stream>>>(x, p0, part0c, x16);
    mid_kernel <<<BB * MIDBLK, 512, 0, stream>>>(p0, ln0w, ln0b, w0, part0c, q1, part1);
    tab_kernel <<<NBC / 4, 256, 0, stream>>>(q1, part1, ln1w, ln1b, ktab);
    conv_kernel<<<NBC, 256, 0, stream>>>(x16, ktab, out);
}

// Round 25
// 61.220 us; speedup vs baseline: 1.0948x; 1.0695x over previous
//
#include <hip/hip_runtime.h>

// Problem constants (B,C,H,W,K) = (32,192,56,56,7)
#define BB 32
#define CC 192
#define HH 56
#define WW 56
#define KS 7
#define HW 3136        // 56*56
#define KK 49
#define CKK 9408       // C*K*K
#define NCELL (BB * CC * KK)   // 301056
#define NBC (BB * CC)          // 6144
#define MIDBLK 24              // mid blocks per sample
#define TABW 56                // u32 words per channel in tap table
#define XP 2048                // u32 words per channel in x16 (32 rowpairs x 64)

typedef _Float16 h2 __attribute__((ext_vector_type(2)));   // for fdot2 only

__device__ __forceinline__ unsigned int pack16(float a, float b) {
    return __builtin_bit_cast(unsigned int, __builtin_amdgcn_cvt_pkrtz(a, b));
}

// ---------------------------------------------------------------------------
// K1: WAVE-PER-CHANNEL pool + x16 emit — FULL 256B-LINE STORES.
// lane = rp*16 + c4 (rp 0..3, c4 0..15). Per group i each 16-lane set writes
// one COMPLETE x16 row (c4=0 -> words 0-3 zeros, c4 1..14 -> body cols,
// c4=15 -> words 60-63 zeros): no partial cache lines -> no RMW. Halo
// rowpairs 0,1,30,31 = one full-row zero store (4 rows/wave). Pool cells via
// shfl_xor(32,16) + shfl_down(1); per-channel LN0 partial.
// ---------------------------------------------------------------------------
__global__ __launch_bounds__(256) void pool_kernel(const float* __restrict__ x,
                                                   float* __restrict__ p0,
                                                   float2* __restrict__ part0c,
                                                   unsigned int* __restrict__ x16) {
    int lane = threadIdx.x & 63;
    int bc   = blockIdx.x * 4 + (threadIdx.x >> 6);
    const float* src = x + (size_t)bc * HW;
    unsigned int* xp = x16 + (size_t)bc * XP;
    int c4 = lane & 15;
    int rp = lane >> 4;
    bool body = (c4 >= 1) && (c4 <= 14);
    int cX = body ? (c4 - 1) : 0;                // clamp: garbage never stored

    // ---- all 14 loads upfront; sched_barrier keeps them in flight ----
    float4 ld[7][2];
#pragma unroll
    for (int i = 0; i < 7; ++i) {
        ld[i][0] = *(const float4*)(src + (8 * i + 2 * rp) * WW + 4 * cX);
        ld[i][1] = *(const float4*)(src + (8 * i + 2 * rp + 1) * WW + 4 * cX);
    }
    __builtin_amdgcn_sched_barrier(0);

    // ---- halo rowpairs 0,1,30,31: full 256B rows of zeros ----
    {
        int hrow = (rp == 0) ? 0 : (rp == 1 ? 1 : (rp == 2 ? 30 : 31));
        *(uint4*)(xp + hrow * 64 + 4 * c4) = make_uint4(0u, 0u, 0u, 0u);
    }

    float sv = 0.f, sq = 0.f;
#pragma unroll
    for (int i = 0; i < 7; ++i) {
        float4 a = ld[i][0], b = ld[i][1];
        uint4 w = make_uint4(0u, 0u, 0u, 0u);
        if (body)
            w = make_uint4(pack16(a.x, b.x), pack16(a.y, b.y),
                           pack16(a.z, b.z), pack16(a.w, b.w));
        // pr2 = 4i+rp+2 holds x rows {2(4i+rp), 2(4i+rp)+1} (natural pairing)
        *(uint4*)(xp + (4 * i + rp + 2) * 64 + 4 * c4) = w;   // full line

        float si = ((a.x + a.y) + (a.z + a.w)) + ((b.x + b.y) + (b.z + b.w));
        si += __shfl_xor(si, 32, 64);            // rp 0<->2, 1<->3
        si += __shfl_xor(si, 16, 64);            // rp 0<->1 -> all 8 rows
        float sj = __shfl_down(si, 1, 64);       // neighbor col-quad
        if (rp == 0 && (c4 & 1) == 1 && c4 <= 13) {
            float pv = (si + sj) * (1.f / 64.f);
            p0[(size_t)bc * KK + i * KS + (c4 >> 1)] = pv;
            sv += pv; sq += pv * pv;
        }
    }

    // ---- per-channel LN0 partial ----
#pragma unroll
    for (int o = 32; o > 0; o >>= 1) {
        sv += __shfl_down(sv, o, 64);
        sq += __shfl_down(sq, o, 64);
    }
    if (lane == 0) part0c[bc] = make_float2(sv, sq);
}

// ---------------------------------------------------------------------------
// K2: LN0-normalize + depthwise 7x7 conv on the 7x7 map, one WAVE per (b,c).
// Stats0 from 192 per-channel partials (3 per lane, exact).
// ---------------------------------------------------------------------------
__global__ __launch_bounds__(512) void mid_kernel(
    const float* __restrict__ p0,
    const float* __restrict__ ln0w, const float* __restrict__ ln0b,
    const float* __restrict__ w0,
    const float2* __restrict__ part0c,
    float* __restrict__ q1,
    float2* __restrict__ part1)
{
    __shared__ float red[16];
    int tid  = threadIdx.x;
    int lane = tid & 63;
    int bc   = blockIdx.x * 8 + (tid >> 6);
    int b = bc / CC;
    int c = bc - b * CC;

    float s0 = 0.f, ss0 = 0.f;
#pragma unroll
    for (int t = 0; t < 3; ++t) {
        float2 p = part0c[b * CC + lane + 64 * t];   // 192 = 3*64 exact
        s0 += p.x; ss0 += p.y;
    }
#pragma unroll
    for (int o = 32; o > 0; o >>= 1) {
        s0  += __shfl_down(s0, o, 64);
        ss0 += __shfl_down(ss0, o, 64);
    }
    s0  = __shfl(s0, 0, 64);
    ss0 = __shfl(ss0, 0, 64);
    float mean = s0 * (1.f / CKK);
    float rstd = rsqrtf(ss0 * (1.f / CKK) - mean * mean + 1e-5f);

    float val = 0.f;
    if (lane < KK)
        val = (p0[(size_t)bc * KK + lane] - mean) * rstd * ln0w[c * KK + lane]
              + ln0b[c * KK + lane];

    int i0 = lane / KS;
    int j0 = lane - i0 * KS;
    const float* wc = w0 + c * KK;

    float acc = 0.f;
#pragma unroll
    for (int u = 0; u < KS; ++u) {
        int ii = i0 + u - 3;
#pragma unroll
        for (int v = 0; v < KS; ++v) {
            int jj = j0 + v - 3;
            bool ok = (ii >= 0) && (ii < KS) && (jj >= 0) && (jj < KS);
            int sl = ok ? (ii * KS + jj) : 0;
            float sv = __shfl(val, sl, 64);
            acc += ok ? sv * wc[u * KS + v] : 0.f;
        }
    }
    if (lane >= KK) acc = 0.f;
    if (lane < KK) q1[(size_t)bc * KK + lane] = acc;

    float s2 = acc, ss2 = acc * acc;
#pragma unroll
    for (int o = 32; o > 0; o >>= 1) {
        s2  += __shfl_down(s2, o, 64);
        ss2 += __shfl_down(ss2, o, 64);
    }
    if (lane == 0) {
        red[(tid >> 6) * 2 + 0] = s2;
        red[(tid >> 6) * 2 + 1] = ss2;
    }
    __syncthreads();
    if (tid == 0) {
        float a = 0.f, q = 0.f;
#pragma unroll
        for (int w = 0; w < 8; ++w) { a += red[2 * w]; q += red[2 * w + 1]; }
        part1[blockIdx.x] = make_float2(a, q);
    }
}

// ---------------------------------------------------------------------------
// K3: tab_kernel — LN1+ReLU taps -> NATURAL-PAIRING tap tables (1 wave/bc).
//   ktab[bc][0..27]  dt[e*7+v] = h2{ e>0 ? kt[2e-1][v] : 0, kt[2e][v] }
//   ktab[bc][28..55] ct[e*7+v] = h2{ kt[2e][v], e<3 ? kt[2e+1][v] : 0 }
// ---------------------------------------------------------------------------
__global__ __launch_bounds__(256) void tab_kernel(
    const float* __restrict__ q1, const float2* __restrict__ part1,
    const float* __restrict__ ln1w, const float* __restrict__ ln1b,
    unsigned int* __restrict__ ktab)
{
    int lane = threadIdx.x & 63;
    int bc   = blockIdx.x * 4 + (threadIdx.x >> 6);
    int b = bc / CC;
    int c = bc - b * CC;

    float s1 = 0.f, ss1 = 0.f;
    if (lane < MIDBLK) {
        float2 p = part1[b * MIDBLK + lane];
        s1 = p.x; ss1 = p.y;
    }
#pragma unroll
    for (int o = 32; o > 0; o >>= 1) {
        s1  += __shfl_down(s1, o, 64);
        ss1 += __shfl_down(ss1, o, 64);
    }
    s1  = __shfl(s1, 0, 64);
    ss1 = __shfl(ss1, 0, 64);
    float m = s1 * (1.f / CKK);
    float r = rsqrtf(ss1 * (1.f / CKK) - m * m + 1e-5f);

    float kt = 0.f;
    if (lane < KK) {
        float v = (q1[(size_t)bc * KK + lane] - m) * r * ln1w[c * KK + lane]
                  + ln1b[c * KK + lane];
        kt = v > 0.f ? v : 0.f;
    }

    bool isDt = lane < 28;
    int idx = isDt ? lane : (lane < TABW ? lane - 28 : 0);
    int e = idx / KS, v = idx - KS * e;
    int iA, iB; bool mA, mB;
    if (isDt) { mA = (e > 0); iA = mA ? (2 * e - 1) * KS + v : 0;
                mB = true;    iB = 2 * e * KS + v; }
    else      { mA = true;    iA = 2 * e * KS + v;
                mB = (e < 3); iB = mB ? (2 * e + 1) * KS + v : 0; }
    float va = __shfl(kt, iA, 64);
    float vb = __shfl(kt, iB, 64);
    unsigned int w = pack16(mA ? va : 0.f, mB ? vb : 0.f);
    if (lane < TABW)
        ktab[(size_t)bc * TABW + lane] = w;
}

// ---------------------------------------------------------------------------
// K4: per-(b,c) depthwise 7x7 SAME conv — NO LDS, NO BARRIER (R20-verified).
// Reads pre-packed x16 directly; lane owns output col; 392 dot2/wave.
// ---------------------------------------------------------------------------
__global__ __launch_bounds__(256) void conv_kernel(
    const unsigned int* __restrict__ x16,
    const unsigned int* __restrict__ ktab,
    float* __restrict__ out)
{
    int bc   = blockIdx.x;
    int tid  = threadIdx.x;
    int lane = tid & 63;
    int wid  = tid >> 6;

    // ---- tap tables (block-uniform -> s_load / SGPRs) ----
    const uint4* tb = (const uint4*)(ktab + (size_t)bc * TABW);
    unsigned int dt[28], ct[28];
#pragma unroll
    for (int i = 0; i < 7; ++i) {
        uint4 t4 = tb[i];
        dt[4 * i + 0] = t4.x; dt[4 * i + 1] = t4.y;
        dt[4 * i + 2] = t4.z; dt[4 * i + 3] = t4.w;
    }
#pragma unroll
    for (int i = 0; i < 7; ++i) {
        uint4 t4 = tb[7 + i];
        ct[4 * i + 0] = t4.x; ct[4 * i + 1] = t4.y;
        ct[4 * i + 2] = t4.z; ct[4 * i + 3] = t4.w;
    }

    int ll = lane < 56 ? lane : 55;      // clamp: lanes 56-63 duplicate lane 55
    const unsigned int* base = x16 + (size_t)bc * XP + (wid * 7) * 64 + ll + 1;

    float accL[7], accH[7];
#pragma unroll
    for (int t = 0; t < 7; ++t) { accL[t] = 0.f; accH[t] = 0.f; }

    unsigned int wa[KS], wb[KS];
#pragma unroll
    for (int j = 0; j < KS; ++j) wa[j] = base[j];          // step s=0

#define H2(u) __builtin_bit_cast(h2, (u))
#define CONV_STEP(S, CUR)                                                     \
    {                                                                         \
        _Pragma("unroll")                                                     \
        for (int e = 0; e < 4; ++e) {                                         \
            int tl = (S) - e;                                                 \
            if (tl >= 0 && tl <= 6) {                                         \
                _Pragma("unroll")                                             \
                for (int vv = 0; vv < KS; ++vv)                               \
                    accL[tl] = __builtin_amdgcn_fdot2(H2(CUR[vv]),            \
                                   H2(dt[e * KS + vv]), accL[tl], false);     \
            }                                                                 \
            int th = (S) - 1 - e;                                             \
            if (th >= 0 && th <= 6) {                                         \
                _Pragma("unroll")                                             \
                for (int vv = 0; vv < KS; ++vv)                               \
                    accH[th] = __builtin_amdgcn_fdot2(H2(CUR[vv]),            \
                                   H2(ct[e * KS + vv]), accH[th], false);     \
            }                                                                 \
        }                                                                     \
    }

#pragma unroll
    for (int ss = 0; ss < 5; ++ss) {
        int s0 = 2 * ss, s1 = 2 * ss + 1;
        {
            const unsigned int* np = base + s1 * 64;
#pragma unroll
            for (int j = 0; j < KS; ++j) wb[j] = np[j];
        }
        CONV_STEP(s0, wa);
        {
            const unsigned int* np = base + (s0 + 2) * 64;
#pragma unroll
            for (int j = 0; j < KS; ++j) wa[j] = np[j];
        }
        CONV_STEP(s1, wb);
    }
    CONV_STEP(10, wa);
#undef CONV_STEP
#undef H2

    if (lane < WW) {
        float* ob = out + (size_t)bc * HW + (wid * 14) * WW + lane;
#pragma unroll
        for (int t = 0; t < 7; ++t) {
            ob[(2 * t) * WW]     = accL[t];
            ob[(2 * t + 1) * WW] = accH[t];
        }
    }
}

// ---------------------------------------------------------------------------
extern "C" void kernel_launch(void* const* d_in, const int* in_sizes, int n_in,
                              void* d_out, int out_size, void* d_ws, size_t ws_size,
                              hipStream_t stream) {
    const float* x    = (const float*)d_in[0];
    const float* ln0w = (const float*)d_in[1];
    const float* ln0b = (const float*)d_in[2];
    const float* w0   = (const float*)d_in[3];
    const float* ln1w = (const float*)d_in[4];
    const float* ln1b = (const float*)d_in[5];
    float* out = (float*)d_out;

    float*  p0     = (float*)d_ws;                     // [NCELL]
    float*  q1     = p0 + NCELL;                       // [NCELL]
    float2* part0c = (float2*)(q1 + NCELL);            // [NBC]
    float2* part1  = part0c + NBC;                     // [BB*MIDBLK]
    unsigned int* ktab = (unsigned int*)(part1 + BB * MIDBLK);   // [NBC*TABW]
    unsigned int* x16  = ktab + (size_t)NBC * TABW;    // [NBC*XP] = 48 MB

    pool_kernel<<<NBC / 4, 256, 0, stream>>>(x, p0, part0c, x16);
    mid_kernel <<<BB * MIDBLK, 512, 0, stream>>>(p0, ln0w, ln0b, w0, part0c, q1, part1);
    tab_kernel <<<NBC / 4, 256, 0, stream>>>(q1, part1, ln1w, ln1b, ktab);
    conv_kernel<<<NBC, 256, 0, stream>>>(x16, ktab, out);
}

// Round 26
// 59.670 us; speedup vs baseline: 1.1232x; 1.0260x over previous
//
#include <hip/hip_runtime.h>

// Problem constants (B,C,H,W,K) = (32,192,56,56,7)
#define BB 32
#define CC 192
#define HH 56
#define WW 56
#define KS 7
#define HW 3136        // 56*56
#define KK 49
#define CKK 9408       // C*K*K
#define NCELL (BB * CC * KK)   // 301056
#define NBC (BB * CC)          // 6144
#define MIDBLK 24              // mid blocks per sample
#define TABW 56                // u32 words per channel in tap table
#define XP 2048                // u32 words per channel in x16 (32 rowpairs x 64)

typedef _Float16 h2 __attribute__((ext_vector_type(2)));   // for fdot2 only

__device__ __forceinline__ unsigned int pack16(float a, float b) {
    return __builtin_bit_cast(unsigned int, __builtin_amdgcn_cvt_pkrtz(a, b));
}

// ---------------------------------------------------------------------------
// K1: WAVE-PER-CHANNEL pool + x16 emit — FULL 256B-LINE STORES (R25-verified).
// ---------------------------------------------------------------------------
__global__ __launch_bounds__(256) void pool_kernel(const float* __restrict__ x,
                                                   float* __restrict__ p0,
                                                   float2* __restrict__ part0c,
                                                   unsigned int* __restrict__ x16) {
    int lane = threadIdx.x & 63;
    int bc   = blockIdx.x * 4 + (threadIdx.x >> 6);
    const float* src = x + (size_t)bc * HW;
    unsigned int* xp = x16 + (size_t)bc * XP;
    int c4 = lane & 15;
    int rp = lane >> 4;
    bool body = (c4 >= 1) && (c4 <= 14);
    int cX = body ? (c4 - 1) : 0;                // clamp: garbage never stored

    // ---- all 14 loads upfront; sched_barrier keeps them in flight ----
    float4 ld[7][2];
#pragma unroll
    for (int i = 0; i < 7; ++i) {
        ld[i][0] = *(const float4*)(src + (8 * i + 2 * rp) * WW + 4 * cX);
        ld[i][1] = *(const float4*)(src + (8 * i + 2 * rp + 1) * WW + 4 * cX);
    }
    __builtin_amdgcn_sched_barrier(0);

    // ---- halo rowpairs 0,1,30,31: full 256B rows of zeros ----
    {
        int hrow = (rp == 0) ? 0 : (rp == 1 ? 1 : (rp == 2 ? 30 : 31));
        *(uint4*)(xp + hrow * 64 + 4 * c4) = make_uint4(0u, 0u, 0u, 0u);
    }

    float sv = 0.f, sq = 0.f;
#pragma unroll
    for (int i = 0; i < 7; ++i) {
        float4 a = ld[i][0], b = ld[i][1];
        uint4 w = make_uint4(0u, 0u, 0u, 0u);
        if (body)
            w = make_uint4(pack16(a.x, b.x), pack16(a.y, b.y),
                           pack16(a.z, b.z), pack16(a.w, b.w));
        // pr2 = 4i+rp+2 holds x rows {2(4i+rp), 2(4i+rp)+1} (natural pairing)
        *(uint4*)(xp + (4 * i + rp + 2) * 64 + 4 * c4) = w;   // full line

        float si = ((a.x + a.y) + (a.z + a.w)) + ((b.x + b.y) + (b.z + b.w));
        si += __shfl_xor(si, 32, 64);            // rp 0<->2, 1<->3
        si += __shfl_xor(si, 16, 64);            // rp 0<->1 -> all 8 rows
        float sj = __shfl_down(si, 1, 64);       // neighbor col-quad
        if (rp == 0 && (c4 & 1) == 1 && c4 <= 13) {
            float pv = (si + sj) * (1.f / 64.f);
            p0[(size_t)bc * KK + i * KS + (c4 >> 1)] = pv;
            sv += pv; sq += pv * pv;
        }
    }

    // ---- per-channel LN0 partial ----
#pragma unroll
    for (int o = 32; o > 0; o >>= 1) {
        sv += __shfl_down(sv, o, 64);
        sq += __shfl_down(sq, o, 64);
    }
    if (lane == 0) part0c[bc] = make_float2(sv, sq);
}

// ---------------------------------------------------------------------------
// K2: LN0-normalize + depthwise 7x7 conv on the 7x7 map, one WAVE per (b,c).
// Stats0 from 192 per-channel partials (3 per lane, exact).
// ---------------------------------------------------------------------------
__global__ __launch_bounds__(512) void mid_kernel(
    const float* __restrict__ p0,
    const float* __restrict__ ln0w, const float* __restrict__ ln0b,
    const float* __restrict__ w0,
    const float2* __restrict__ part0c,
    float* __restrict__ q1,
    float2* __restrict__ part1)
{
    __shared__ float red[16];
    int tid  = threadIdx.x;
    int lane = tid & 63;
    int bc   = blockIdx.x * 8 + (tid >> 6);
    int b = bc / CC;
    int c = bc - b * CC;

    float s0 = 0.f, ss0 = 0.f;
#pragma unroll
    for (int t = 0; t < 3; ++t) {
        float2 p = part0c[b * CC + lane + 64 * t];   // 192 = 3*64 exact
        s0 += p.x; ss0 += p.y;
    }
#pragma unroll
    for (int o = 32; o > 0; o >>= 1) {
        s0  += __shfl_down(s0, o, 64);
        ss0 += __shfl_down(ss0, o, 64);
    }
    s0  = __shfl(s0, 0, 64);
    ss0 = __shfl(ss0, 0, 64);
    float mean = s0 * (1.f / CKK);
    float rstd = rsqrtf(ss0 * (1.f / CKK) - mean * mean + 1e-5f);

    float val = 0.f;
    if (lane < KK)
        val = (p0[(size_t)bc * KK + lane] - mean) * rstd * ln0w[c * KK + lane]
              + ln0b[c * KK + lane];

    int i0 = lane / KS;
    int j0 = lane - i0 * KS;
    const float* wc = w0 + c * KK;

    float acc = 0.f;
#pragma unroll
    for (int u = 0; u < KS; ++u) {
        int ii = i0 + u - 3;
#pragma unroll
        for (int v = 0; v < KS; ++v) {
            int jj = j0 + v - 3;
            bool ok = (ii >= 0) && (ii < KS) && (jj >= 0) && (jj < KS);
            int sl = ok ? (ii * KS + jj) : 0;
            float sv = __shfl(val, sl, 64);
            acc += ok ? sv * wc[u * KS + v] : 0.f;
        }
    }
    if (lane >= KK) acc = 0.f;
    if (lane < KK) q1[(size_t)bc * KK + lane] = acc;

    float s2 = acc, ss2 = acc * acc;
#pragma unroll
    for (int o = 32; o > 0; o >>= 1) {
        s2  += __shfl_down(s2, o, 64);
        ss2 += __shfl_down(ss2, o, 64);
    }
    if (lane == 0) {
        red[(tid >> 6) * 2 + 0] = s2;
        red[(tid >> 6) * 2 + 1] = ss2;
    }
    __syncthreads();
    if (tid == 0) {
        float a = 0.f, q = 0.f;
#pragma unroll
        for (int w = 0; w < 8; ++w) { a += red[2 * w]; q += red[2 * w + 1]; }
        part1[blockIdx.x] = make_float2(a, q);
    }
}

// ---------------------------------------------------------------------------
// K3: tab_kernel — LN1+ReLU taps -> NATURAL-PAIRING tap tables (1 wave/bc).
//   ktab[bc][0..27]  dt[e*7+v] = h2{ e>0 ? kt[2e-1][v] : 0, kt[2e][v] }
//   ktab[bc][28..55] ct[e*7+v] = h2{ kt[2e][v], e<3 ? kt[2e+1][v] : 0 }
// ---------------------------------------------------------------------------
__global__ __launch_bounds__(256) void tab_kernel(
    const float* __restrict__ q1, const float2* __restrict__ part1,
    const float* __restrict__ ln1w, const float* __restrict__ ln1b,
    unsigned int* __restrict__ ktab)
{
    int lane = threadIdx.x & 63;
    int bc   = blockIdx.x * 4 + (threadIdx.x >> 6);
    int b = bc / CC;
    int c = bc - b * CC;

    float s1 = 0.f, ss1 = 0.f;
    if (lane < MIDBLK) {
        float2 p = part1[b * MIDBLK + lane];
        s1 = p.x; ss1 = p.y;
    }
#pragma unroll
    for (int o = 32; o > 0; o >>= 1) {
        s1  += __shfl_down(s1, o, 64);
        ss1 += __shfl_down(ss1, o, 64);
    }
    s1  = __shfl(s1, 0, 64);
    ss1 = __shfl(ss1, 0, 64);
    float m = s1 * (1.f / CKK);
    float r = rsqrtf(ss1 * (1.f / CKK) - m * m + 1e-5f);

    float kt = 0.f;
    if (lane < KK) {
        float v = (q1[(size_t)bc * KK + lane] - m) * r * ln1w[c * KK + lane]
                  + ln1b[c * KK + lane];
        kt = v > 0.f ? v : 0.f;
    }

    bool isDt = lane < 28;
    int idx = isDt ? lane : (lane < TABW ? lane - 28 : 0);
    int e = idx / KS, v = idx - KS * e;
    int iA, iB; bool mA, mB;
    if (isDt) { mA = (e > 0); iA = mA ? (2 * e - 1) * KS + v : 0;
                mB = true;    iB = 2 * e * KS + v; }
    else      { mA = true;    iA = 2 * e * KS + v;
                mB = (e < 3); iB = mB ? (2 * e + 1) * KS + v : 0; }
    float va = __shfl(kt, iA, 64);
    float vb = __shfl(kt, iB, 64);
    unsigned int w = pack16(mA ? va : 0.f, mB ? vb : 0.f);
    if (lane < TABW)
        ktab[(size_t)bc * TABW + lane] = w;
}

// ---------------------------------------------------------------------------
// K4: per-(b,c) depthwise 7x7 SAME conv — NO LDS, NO BARRIER; output stores
// are NON-TEMPORAL (out is write-only dead data -> keep x/x16 L3-resident).
// ---------------------------------------------------------------------------
__global__ __launch_bounds__(256) void conv_kernel(
    const unsigned int* __restrict__ x16,
    const unsigned int* __restrict__ ktab,
    float* __restrict__ out)
{
    int bc   = blockIdx.x;
    int tid  = threadIdx.x;
    int lane = tid & 63;
    int wid  = tid >> 6;

    // ---- tap tables (block-uniform -> s_load / SGPRs) ----
    const uint4* tb = (const uint4*)(ktab + (size_t)bc * TABW);
    unsigned int dt[28], ct[28];
#pragma unroll
    for (int i = 0; i < 7; ++i) {
        uint4 t4 = tb[i];
        dt[4 * i + 0] = t4.x; dt[4 * i + 1] = t4.y;
        dt[4 * i + 2] = t4.z; dt[4 * i + 3] = t4.w;
    }
#pragma unroll
    for (int i = 0; i < 7; ++i) {
        uint4 t4 = tb[7 + i];
        ct[4 * i + 0] = t4.x; ct[4 * i + 1] = t4.y;
        ct[4 * i + 2] = t4.z; ct[4 * i + 3] = t4.w;
    }

    int ll = lane < 56 ? lane : 55;      // clamp: lanes 56-63 duplicate lane 55
    const unsigned int* base = x16 + (size_t)bc * XP + (wid * 7) * 64 + ll + 1;

    float accL[7], accH[7];
#pragma unroll
    for (int t = 0; t < 7; ++t) { accL[t] = 0.f; accH[t] = 0.f; }

    unsigned int wa[KS], wb[KS];
#pragma unroll
    for (int j = 0; j < KS; ++j) wa[j] = base[j];          // step s=0

#define H2(u) __builtin_bit_cast(h2, (u))
#define CONV_STEP(S, CUR)                                                     \
    {                                                                         \
        _Pragma("unroll")                                                     \
        for (int e = 0; e < 4; ++e) {                                         \
            int tl = (S) - e;                                                 \
            if (tl >= 0 && tl <= 6) {                                         \
                _Pragma("unroll")                                             \
                for (int vv = 0; vv < KS; ++vv)                               \
                    accL[tl] = __builtin_amdgcn_fdot2(H2(CUR[vv]),            \
                                   H2(dt[e * KS + vv]), accL[tl], false);     \
            }                                                                 \
            int th = (S) - 1 - e;                                             \
            if (th >= 0 && th <= 6) {                                         \
                _Pragma("unroll")                                             \
                for (int vv = 0; vv < KS; ++vv)                               \
                    accH[th] = __builtin_amdgcn_fdot2(H2(CUR[vv]),            \
                                   H2(ct[e * KS + vv]), accH[th], false);     \
            }                                                                 \
        }                                                                     \
    }

#pragma unroll
    for (int ss = 0; ss < 5; ++ss) {
        int s0 = 2 * ss, s1 = 2 * ss + 1;
        {
            const unsigned int* np = base + s1 * 64;
#pragma unroll
            for (int j = 0; j < KS; ++j) wb[j] = np[j];
        }
        CONV_STEP(s0, wa);
        {
            const unsigned int* np = base + (s0 + 2) * 64;
#pragma unroll
            for (int j = 0; j < KS; ++j) wa[j] = np[j];
        }
        CONV_STEP(s1, wb);
    }
    CONV_STEP(10, wa);
#undef CONV_STEP
#undef H2

    if (lane < WW) {
        float* ob = out + (size_t)bc * HW + (wid * 14) * WW + lane;
#pragma unroll
        for (int t = 0; t < 7; ++t) {
            __builtin_nontemporal_store(accL[t], ob + (2 * t) * WW);
            __builtin_nontemporal_store(accH[t], ob + (2 * t + 1) * WW);
        }
    }
}

// ---------------------------------------------------------------------------
extern "C" void kernel_launch(void* const* d_in, const int* in_sizes, int n_in,
                              void* d_out, int out_size, void* d_ws, size_t ws_size,
                              hipStream_t stream) {
    const float* x    = (const float*)d_in[0];
    const float* ln0w = (const float*)d_in[1];
    const float* ln0b = (const float*)d_in[2];
    const float* w0   = (const float*)d_in[3];
    const float* ln1w = (const float*)d_in[4];
    const float* ln1b = (const float*)d_in[5];
    float* out = (float*)d_out;

    float*  p0     = (float*)d_ws;                     // [NCELL]
    float*  q1     = p0 + NCELL;                       // [NCELL]
    float2* part0c = (float2*)(q1 + NCELL);            // [NBC]
    float2* part1  = part0c + NBC;                     // [BB*MIDBLK]
    unsigned int* ktab = (unsigned int*)(part1 + BB * MIDBLK);   // [NBC*TABW]
    unsigned int* x16  = ktab + (size_t)NBC * TABW;    // [NBC*XP] = 48 MB

    pool_kernel<<<NBC / 4, 256, 0, stream>>>(x, p0, part0c, x16);
    mid_kernel <<<BB * MIDBLK, 512, 0, stream>>>(p0, ln0w, ln0b, w0, part0c, q1, part1);
    tab_kernel <<<NBC / 4, 256, 0, stream>>>(q1, part1, ln1w, ln1b, ktab);
    conv_kernel<<<NBC, 256, 0, stream>>>(x16, ktab, out);
}